// Round 1
// baseline (1229.892 us; speedup 1.0000x reference)
//
#include <hip/hip_runtime.h>

#define NN 50000
#define NE 800000

typedef __attribute__((ext_vector_type(8))) short bf16x8;
typedef __attribute__((ext_vector_type(4))) float f32x4;

__device__ __forceinline__ unsigned short f2bf(float f) {
    union { float f; unsigned u; } v; v.f = f;
    unsigned r = v.u + 0x7FFFu + ((v.u >> 16) & 1u);
    return (unsigned short)(r >> 16);
}

// padded tiled LDS layout: element (node m, local k) -> word index.
// kk = k>>5 (32-k block), r = k&31, group = r>>3 (4 groups/kk), j = r&7.
// group stride 132 (=128+4 pad words) breaks bank-conflict alignment.
__device__ __forceinline__ int hb_idx(int kk, int r, int m) {
    return kk*528 + (r >> 3)*132 + m*8 + (r & 7);
}

// ---------------- setup kernels ----------------
__global__ __launch_bounds__(256) void k_zero(int* degi, int* cur, float* stats) {
    int i = blockIdx.x*256 + threadIdx.x;
    int stride = gridDim.x*256;
    for (int j = i; j < NN; j += stride) { degi[j] = 0; cur[j] = 0; }
    if (i < 384) stats[i] = 0.f;
}

__global__ __launch_bounds__(256) void k_hist(const int* __restrict__ dst, int* degi) {
    int e = blockIdx.x*256 + threadIdx.x;
    if (e < NE) atomicAdd(&degi[dst[e]], 1);
}

__global__ __launch_bounds__(256) void k_scan_block(const int* __restrict__ degi,
                                                    int* off, int* bsum) {
    __shared__ int sh[256];
    int t = threadIdx.x;
    int base = blockIdx.x * 1024;
    int v[4]; int s = 0;
#pragma unroll
    for (int j = 0; j < 4; j++) {
        int idx = base + t*4 + j;
        v[j] = (idx < NN) ? degi[idx] : 0;
        s += v[j];
    }
    sh[t] = s; __syncthreads();
    for (int ofs = 1; ofs < 256; ofs <<= 1) {
        int x = (t >= ofs) ? sh[t - ofs] : 0;
        __syncthreads();
        sh[t] += x;
        __syncthreads();
    }
    int ex = sh[t] - s;
#pragma unroll
    for (int j = 0; j < 4; j++) {
        int idx = base + t*4 + j;
        if (idx < NN) off[idx] = ex;
        ex += v[j];
    }
    if (t == 255) bsum[blockIdx.x] = sh[255];
}

__global__ __launch_bounds__(256) void k_scan_top(const int* __restrict__ bsum,
                                                  int* bpre, int nb) {
    __shared__ int sh[256];
    int t = threadIdx.x;
    int s = (t < nb) ? bsum[t] : 0;
    sh[t] = s; __syncthreads();
    for (int ofs = 1; ofs < 256; ofs <<= 1) {
        int x = (t >= ofs) ? sh[t - ofs] : 0;
        __syncthreads();
        sh[t] += x;
        __syncthreads();
    }
    if (t < nb) bpre[t] = sh[t] - s;
}

__global__ __launch_bounds__(256) void k_scan_add(int* off, const int* __restrict__ bpre) {
    int i = blockIdx.x*256 + threadIdx.x;
    if (i < NN) off[i] += bpre[i >> 10];
    if (i == 0) off[NN] = NE;
}

__global__ __launch_bounds__(256) void k_scatter(const int* __restrict__ src,
                                                 const int* __restrict__ dst,
                                                 const float* __restrict__ ea,
                                                 const int* __restrict__ off, int* cur,
                                                 int* es_src, int* es_fib, float2* es_frac) {
    int e = blockIdx.x*256 + threadIdx.x;
    if (e >= NE) return;
    int d = dst[e];
    int p = off[d] + atomicAdd(&cur[d], 1);
    es_src[p] = src[e];
    float v0 = ea[2*e]     * 4.f;
    float v1 = ea[2*e + 1] * 4.f;
    float f0 = fminf(fmaxf(floorf(v0), 0.f), 3.f);
    float f1 = fminf(fmaxf(floorf(v1), 0.f), 3.f);
    es_fib[p] = (int)f0 + 5*(int)f1;
    es_frac[p] = make_float2(v0 - f0, v1 - f1);
}

// Pre-tile [W ; root] (f32, row-major [K,64]) into MFMA-B bf16 layout:
// Wb[((kk*4+w)*64+lane)*8 + j] = src[k = kk*32+(lane>>4)*8+j][co = 16w+(lane&15)]
__global__ __launch_bounds__(256) void k_wprep(const float* __restrict__ W,
                                               const float* __restrict__ root,
                                               int KTC, unsigned short* Wb) {
    int tid = blockIdx.x*256 + threadIdx.x;
    int lane = tid & 63, w = (tid >> 6) & 3, kk = tid >> 8;
    int co = 16*w + (lane & 15);
    int kbase = kk*32 + ((lane >> 4) * 8);
    union { unsigned short s[8]; uint4 v; } u;
#pragma unroll
    for (int j = 0; j < 8; j++) {
        int k = kbase + j;
        float val = (k < KTC) ? W[(size_t)k*64 + co] : root[(size_t)(k - KTC)*64 + co];
        u.s[j] = f2bf(val);
    }
    *(uint4*)(Wb + (size_t)tid * 8) = u.v;
}

// ---------------- fused spline-conv (bucket + MFMA) ----------------
// Block = 256 threads (4 waves), 16 nodes/block. Wave w owns nodes w,w+4,w+8,w+12
// (no LDS atomics needed: lanes own distinct ci; corner-halves write disjoint wi).
template<int CIN, int KT, int NPASS>
__global__ __launch_bounds__(256) void k_conv(
        const float* __restrict__ X,
        const int* __restrict__ off,
        const int* __restrict__ degi,
        const int* __restrict__ es_src,
        const int* __restrict__ es_fib,
        const float2* __restrict__ es_frac,
        const unsigned short* __restrict__ Wb,
        const float* __restrict__ bias,
        float* __restrict__ agg) {
    constexpr int WI_SPLIT = (NPASS == 2) ? 13 : KT;
    constexpr int DIMS0 = WI_SPLIT*CIN + ((NPASS == 1) ? CIN : 0);
    constexpr int DIMS1 = (NPASS == 2) ? ((KT - WI_SPLIT)*CIN + CIN) : 32;
    constexpr int MAXDIMS = (DIMS0 > DIMS1) ? DIMS0 : DIMS1;
    constexpr int MAXWORDS = (MAXDIMS/32) * 528;

    __shared__ float hb[MAXWORDS];
    __shared__ float rdeg[16];

    const int t = threadIdx.x;
    const int lane = t & 63;
    const int w = t >> 6;
    const int n0 = blockIdx.x * 16;

    if (t < 16) {
        int d = degi[n0 + t];
        rdeg[t] = 1.0f / (float)(d > 0 ? d : 1);
    }

    f32x4 acc = {0.f, 0.f, 0.f, 0.f};
    int kkglob = 0;

    for (int pass = 0; pass < NPASS; ++pass) {
        const int wi_lo = (pass == 0) ? 0 : WI_SPLIT;
        const int wi_hi = (pass == 0) ? WI_SPLIT : KT;
        const bool last = (pass == NPASS - 1);
        const int bdims = (wi_hi - wi_lo) * CIN;
        const int dims  = bdims + (last ? CIN : 0);
        const int nwords = (dims >> 5) * 528;
        const int ksteps = dims >> 5;

        __syncthreads();
        for (int i = t; i < nwords; i += 256) hb[i] = 0.f;
        __syncthreads();

        // ---- phase A: bucket accumulate from sorted edge lists ----
        for (int gi = 0; gi < 4; ++gi) {
            const int g = w + gi*4;
            const int n = n0 + g;
            const int ebeg = off[n], eend = off[n + 1];
            if (CIN == 64) {
                const int ci = lane;
                for (int i = ebeg; i < eend; ++i) {
                    int s = es_src[i];
                    float xv = X[(size_t)s*64 + ci];
                    int fib = es_fib[i];
                    float2 fr = es_frac[i];
#pragma unroll
                    for (int c4 = 0; c4 < 4; ++c4) {
                        int s0 = c4 & 1, s1 = c4 >> 1;
                        int wi = fib + s0 + 5*s1;
                        if (wi >= wi_lo && wi < wi_hi) {
                            float basis = (s0 ? fr.x : 1.f - fr.x) * (s1 ? fr.y : 1.f - fr.y);
                            int kl = (wi - wi_lo)*64 + ci;
                            hb[hb_idx(kl >> 5, kl & 31, g)] += basis * xv;
                        }
                    }
                }
            } else if (KT == 25) {  // CIN==32, single pass
                const int ci = lane & 31;
                const int s1 = lane >> 5;   // lane halves take disjoint wi sets
                for (int i = ebeg; i < eend; ++i) {
                    int s = es_src[i];
                    float xv = X[(size_t)s*32 + ci];
                    int fib = es_fib[i];
                    float2 fr = es_frac[i];
                    float bb1 = s1 ? fr.y : 1.f - fr.y;
#pragma unroll
                    for (int s0 = 0; s0 < 2; ++s0) {
                        float basis = (s0 ? fr.x : 1.f - fr.x) * bb1;
                        int wi = fib + s0 + 5*s1;
                        int kl = wi*32 + ci;
                        hb[hb_idx(kl >> 5, kl & 31, g)] += basis * xv;
                    }
                }
            } else {  // KT == 1, CIN == 32: plain sum aggregation
                if (lane < 32) {
                    const int ci = lane;
                    for (int i = ebeg; i < eend; ++i) {
                        int s = es_src[i];
                        hb[hb_idx(0, ci, g)] += X[(size_t)s*32 + ci];
                    }
                }
            }
        }
        __syncthreads();

        // ---- scale bucket part by 1/deg ----
        for (int i = t; i < bdims*16; i += 256) {
            int kl = i >> 4, m = i & 15;
            hb[hb_idx(kl >> 5, kl & 31, m)] *= rdeg[m];
        }
        // ---- append X rows (folds x@root into the MFMA, unscaled) ----
        if (last) {
            for (int i = t; i < 16*CIN; i += 256) {
                int m = i / CIN, ci = i % CIN;
                int kl = bdims + ci;
                hb[hb_idx(kl >> 5, kl & 31, m)] = X[(size_t)(n0 + m)*CIN + ci];
            }
        }
        __syncthreads();

        // ---- MFMA K-loop: A from LDS (f32->bf16), B pre-tiled bf16 from L2 ----
        for (int kk = 0; kk < ksteps; ++kk) {
            const float* ap = &hb[kk*528 + (lane >> 4)*132 + (lane & 15)*8];
            union { unsigned short us[8]; bf16x8 v; } au;
#pragma unroll
            for (int j = 0; j < 8; ++j) au.us[j] = f2bf(ap[j]);
            bf16x8 bv = *(const bf16x8*)(Wb + (size_t)(((kkglob + kk)*4 + w)*64 + lane)*8);
            acc = __builtin_amdgcn_mfma_f32_16x16x32_bf16(au.v, bv, acc, 0, 0, 0);
        }
        kkglob += ksteps;
    }

    // ---- epilogue: + bias, store agg (C/D: col=lane&15, row=(lane>>4)*4+reg) ----
    const int co = 16*w + (lane & 15);
    const float bvv = bias[co];
#pragma unroll
    for (int r = 0; r < 4; ++r) {
        int m = (lane >> 4)*4 + r;
        agg[(size_t)(n0 + m)*64 + co] = acc[r] + bvv;
    }
}

// ---------------- batch norm ----------------
__global__ __launch_bounds__(256) void k_bnstats(const float* __restrict__ agg, float* stats) {
    __shared__ float sh0[256], sh1[256];
    int t = threadIdx.x;
    float s = 0.f, ss = 0.f;
    int stride = gridDim.x * 256;
    for (int i = blockIdx.x*256 + t; i < NN*64; i += stride) {
        float v = agg[i];
        s += v; ss += v*v;
    }
    sh0[t] = s; sh1[t] = ss;
    __syncthreads();
    if (t < 64) {
        float a = sh0[t] + sh0[t+64] + sh0[t+128] + sh0[t+192];
        float b = sh1[t] + sh1[t+64] + sh1[t+128] + sh1[t+192];
        atomicAdd(&stats[t], a);
        atomicAdd(&stats[64 + t], b);
    }
}

__device__ __forceinline__ float eluf(float u) { return u > 0.f ? u : expm1f(u); }

__global__ __launch_bounds__(256) void k_bn_elu(const float* __restrict__ agg,
                                                const float* __restrict__ stats,
                                                const float* __restrict__ gamma,
                                                const float* __restrict__ beta,
                                                float* __restrict__ out) {
    int i = blockIdx.x*256 + threadIdx.x;
    if (i >= NN*16) return;
    float4 v = ((const float4*)agg)[i];
    float r[4] = {v.x, v.y, v.z, v.w};
    int c0 = (i << 2) & 63;
#pragma unroll
    for (int j = 0; j < 4; j++) {
        int c = c0 + j;
        float mu = stats[c] * (1.f/NN);
        float var = stats[64 + c] * (1.f/NN) - mu*mu;
        float sc = gamma[c] * rsqrtf(fmaxf(var, 0.f) + 1e-5f);
        r[j] = eluf((r[j] - mu)*sc + beta[c]);
    }
    ((float4*)out)[i] = make_float4(r[0], r[1], r[2], r[3]);
}

__global__ __launch_bounds__(256) void k_bn_final(const float* __restrict__ a2,
                                                  const float* __restrict__ st2,
                                                  const float* __restrict__ g2,
                                                  const float* __restrict__ be2,
                                                  const float* __restrict__ as,
                                                  const float* __restrict__ sts,
                                                  const float* __restrict__ gs,
                                                  const float* __restrict__ bes,
                                                  float* __restrict__ out) {
    int i = blockIdx.x*256 + threadIdx.x;
    if (i >= NN*16) return;
    float4 v2 = ((const float4*)a2)[i];
    float4 vs = ((const float4*)as)[i];
    float r2v[4] = {v2.x, v2.y, v2.z, v2.w};
    float rsv[4] = {vs.x, vs.y, vs.z, vs.w};
    float o[4];
    int c0 = (i << 2) & 63;
#pragma unroll
    for (int j = 0; j < 4; j++) {
        int c = c0 + j;
        float mu2 = st2[c] * (1.f/NN);
        float var2 = st2[64 + c] * (1.f/NN) - mu2*mu2;
        float sc2 = g2[c] * rsqrtf(fmaxf(var2, 0.f) + 1e-5f);
        float mus = sts[c] * (1.f/NN);
        float vars = sts[64 + c] * (1.f/NN) - mus*mus;
        float scs = gs[c] * rsqrtf(fmaxf(vars, 0.f) + 1e-5f);
        float u = (r2v[j] - mu2)*sc2 + be2[c] + (rsv[j] - mus)*scs + bes[c];
        o[j] = eluf(u);
    }
    ((float4*)out)[i] = make_float4(o[0], o[1], o[2], o[3]);
}

extern "C" void kernel_launch(void* const* d_in, const int* in_sizes, int n_in,
                              void* d_out, int out_size, void* d_ws, size_t ws_size,
                              hipStream_t stream) {
    const float* x   = (const float*)d_in[0];
    const int*   ei  = (const int*)d_in[1];
    const float* ea  = (const float*)d_in[2];
    const float* w1  = (const float*)d_in[3];
    const float* r1  = (const float*)d_in[4];
    const float* b1  = (const float*)d_in[5];
    const float* g1  = (const float*)d_in[6];
    const float* be1 = (const float*)d_in[7];
    const float* w2  = (const float*)d_in[8];
    const float* r2  = (const float*)d_in[9];
    const float* b2  = (const float*)d_in[10];
    const float* g2  = (const float*)d_in[11];
    const float* be2 = (const float*)d_in[12];
    const float* wsN = (const float*)d_in[13];
    const float* rs  = (const float*)d_in[14];
    const float* bs  = (const float*)d_in[15];
    const float* gs  = (const float*)d_in[16];
    const float* bes = (const float*)d_in[17];
    const int* srcp = ei;
    const int* dstp = ei + NE;

    char* wsb = (char*)d_ws;
    size_t o = 0;
    auto alloc = [&](size_t bytes) -> char* {
        char* p = wsb + o;
        o += (bytes + 255) & ~(size_t)255;
        return p;
    };
    int*    degi    = (int*)   alloc((size_t)NN * 4);
    int*    cur     = (int*)   alloc((size_t)NN * 4);
    int*    off     = (int*)   alloc((size_t)(NN + 1) * 4);
    int*    bsum    = (int*)   alloc(256 * 4);
    int*    bpre    = (int*)   alloc(256 * 4);
    int*    es_src  = (int*)   alloc((size_t)NE * 4);
    int*    es_fib  = (int*)   alloc((size_t)NE * 4);
    float2* es_frac = (float2*)alloc((size_t)NE * 8);
    unsigned short* Wb1 = (unsigned short*)alloc(26 * 4096);
    unsigned short* WbS = (unsigned short*)alloc(2 * 4096);
    unsigned short* Wb2 = (unsigned short*)alloc(52 * 4096);
    float*  agg1    = (float*) alloc((size_t)NN * 64 * 4);  // reused for conv2 output
    float*  aggS    = (float*) alloc((size_t)NN * 64 * 4);
    float*  h1      = (float*) alloc((size_t)NN * 64 * 4);
    float*  stats   = (float*) alloc(384 * 4);
    (void)ws_size; (void)in_sizes; (void)n_in; (void)out_size;

    float* out = (float*)d_out;

    k_zero<<<196, 256, 0, stream>>>(degi, cur, stats);
    k_hist<<<3125, 256, 0, stream>>>(dstp, degi);
    k_scan_block<<<49, 256, 0, stream>>>(degi, off, bsum);
    k_scan_top<<<1, 256, 0, stream>>>(bsum, bpre, 49);
    k_scan_add<<<196, 256, 0, stream>>>(off, bpre);
    k_scatter<<<3125, 256, 0, stream>>>(srcp, dstp, ea, off, cur, es_src, es_fib, es_frac);

    k_wprep<<<26, 256, 0, stream>>>(w1, r1, 800, Wb1);
    k_wprep<<<2, 256, 0, stream>>>(wsN, rs, 32, WbS);
    k_wprep<<<52, 256, 0, stream>>>(w2, r2, 1600, Wb2);

    k_conv<32, 25, 1><<<3125, 256, 0, stream>>>(x, off, degi, es_src, es_fib, es_frac,
                                                Wb1, b1, agg1);
    k_conv<32, 1, 1><<<3125, 256, 0, stream>>>(x, off, degi, es_src, es_fib, es_frac,
                                               WbS, bs, aggS);
    k_bnstats<<<256, 256, 0, stream>>>(agg1, stats);
    k_bn_elu<<<3125, 256, 0, stream>>>(agg1, stats, g1, be1, h1);

    k_conv<64, 25, 2><<<3125, 256, 0, stream>>>(h1, off, degi, es_src, es_fib, es_frac,
                                                Wb2, b2, agg1);
    k_bnstats<<<256, 256, 0, stream>>>(agg1, stats + 128);
    k_bnstats<<<256, 256, 0, stream>>>(aggS, stats + 256);
    k_bn_final<<<3125, 256, 0, stream>>>(agg1, stats + 128, g2, be2,
                                         aggS, stats + 256, gs, bes, out);
}